// Round 2
// baseline (791.561 us; speedup 1.0000x reference)
//
#include <hip/hip_runtime.h>

// OpenLSTM: B=64, T=8192, nstep=4096, HIDDEN=16, PROJ=2, INPUT=2
// Phase 1 (t<4096): parallel, gates from W_ih@x+b only, c1=i*g.
// Phase 2 (t>=4096): sequential scan, latency-bound. 16 lanes per batch,
// all state in registers, DPP rotation reduce for the 16->2 projection.

#define BB   64
#define TT   8192
#define NST  4096
#define PF   16

#if __has_builtin(__builtin_amdgcn_exp2f)
__device__ __forceinline__ float fast_exp2(float x) { return __builtin_amdgcn_exp2f(x); }
#else
__device__ __forceinline__ float fast_exp2(float x) { return exp2f(x); }
#endif
#if __has_builtin(__builtin_amdgcn_rcpf)
__device__ __forceinline__ float fast_rcp(float x) { return __builtin_amdgcn_rcpf(x); }
#else
__device__ __forceinline__ float fast_rcp(float x) { return 1.0f / x; }
#endif

// add value rotated by N within each 16-lane row (row_ror:N = 0x120|N)
template <int CTRL>
__device__ __forceinline__ float rr_add(float x) {
  int r = __builtin_amdgcn_update_dpp(0, __builtin_bit_cast(int, x), CTRL, 0xF, 0xF, true);
  return x + __builtin_bit_cast(float, r);
}

struct GW {
  float wii0, wii1, wif0, wif1, wig0, wig1, wio0, wio1;   // -log2e scaled W_ih rows
  float whi0, whi1, whf0, whf1, whg0, whg1, who0, who1;   // -log2e scaled W_hh rows
  float bi, bf, bg, bo;                                   // scaled combined bias
  float whr0, whr1;                                       // W_hr columns for this hh
};

template <bool NEED_HH>
__device__ __forceinline__ void load_w(const float* __restrict__ Wih,
                                       const float* __restrict__ Whh,
                                       const float* __restrict__ bih,
                                       const float* __restrict__ bhh,
                                       const float* __restrict__ Whr,
                                       int hh, GW& w) {
  const float S1 = -1.4426950408889634f;   // -log2(e)   (sigmoid gates)
  const float S2 = -2.8853900817779268f;   // -2*log2(e) (tanh gate)
  const int ri = hh, rf = hh + 16, rg = hh + 32, ro = hh + 48;
  w.wii0 = Wih[2 * ri] * S1;  w.wii1 = Wih[2 * ri + 1] * S1;
  w.wif0 = Wih[2 * rf] * S1;  w.wif1 = Wih[2 * rf + 1] * S1;
  w.wig0 = Wih[2 * rg] * S2;  w.wig1 = Wih[2 * rg + 1] * S2;
  w.wio0 = Wih[2 * ro] * S1;  w.wio1 = Wih[2 * ro + 1] * S1;
  w.bi = (bih[ri] + bhh[ri]) * S1;
  w.bf = (bih[rf] + bhh[rf]) * S1;
  w.bg = (bih[rg] + bhh[rg]) * S2;
  w.bo = (bih[ro] + bhh[ro]) * S1;
  if (NEED_HH) {
    w.whi0 = Whh[2 * ri] * S1;  w.whi1 = Whh[2 * ri + 1] * S1;
    w.whf0 = Whh[2 * rf] * S1;  w.whf1 = Whh[2 * rf + 1] * S1;
    w.whg0 = Whh[2 * rg] * S2;  w.whg1 = Whh[2 * rg + 1] * S2;
    w.who0 = Whh[2 * ro] * S1;  w.who1 = Whh[2 * ro + 1] * S1;
  } else {
    w.whi0 = w.whi1 = w.whf0 = w.whf1 = 0.f;
    w.whg0 = w.whg1 = w.who0 = w.who1 = 0.f;
  }
  w.whr0 = Whr[hh];
  w.whr1 = Whr[16 + hh];
}

// Given scaled pre-activations s* (already = -log2e * preact), update c and
// produce h (broadcast to all 16 lanes of the row via DPP rotation reduce).
__device__ __forceinline__ void gates_tail(const GW& w, float si, float sf,
                                           float sg, float so,
                                           float& h0, float& h1, float& c) {
  const float gi = fast_rcp(1.f + fast_exp2(si));                 // sigmoid(i)
  const float gf = fast_rcp(1.f + fast_exp2(sf));                 // sigmoid(f)
  const float gg = fmaf(2.f, fast_rcp(1.f + fast_exp2(sg)), -1.f);// tanh(g)
  const float go = fast_rcp(1.f + fast_exp2(so));                 // sigmoid(o)
  c = fmaf(gf, c, gi * gg);
  // tanh(c) = 1 - 2/(exp2(2*log2e*c)+1)
  const float tc = fmaf(-2.f, fast_rcp(1.f + fast_exp2(c * 2.8853900817779268f)), 1.f);
  const float v = go * tc;
  float p0 = v * w.whr0;
  float p1 = v * w.whr1;
  p0 = rr_add<0x128>(p0); p1 = rr_add<0x128>(p1);   // ror 8
  p0 = rr_add<0x124>(p0); p1 = rr_add<0x124>(p1);   // ror 4
  p0 = rr_add<0x122>(p0); p1 = rr_add<0x122>(p1);   // ror 2
  p0 = rr_add<0x121>(p0); p1 = rr_add<0x121>(p1);   // ror 1
  h0 = p0;  // every lane now holds the full sum
  h1 = p1;
}

__global__ __launch_bounds__(256) void openlstm_kernel(
    const float* __restrict__ u_train, const float* __restrict__ y_train,
    const float* __restrict__ Wih, const float* __restrict__ Whh,
    const float* __restrict__ bih, const float* __restrict__ bhh,
    const float* __restrict__ Whr, float* __restrict__ out) {
  const int tid = threadIdx.x;
  const int hh  = tid & 15;
  const int grp = tid >> 4;   // 0..15 within block

  if (blockIdx.x < 4) {
    // ---------------- Phase 2: sequential scan ----------------
    const int bb = blockIdx.x * 16 + grp;   // batch 0..63
    GW w;
    load_w<true>(Wih, Whh, bih, bhh, Whr, hh, w);

    float h0 = 0.f, h1 = 0.f, c = 0.f;
    {
      // initial carry from y_train[bb, NST-1, :]  (h=0, c=0 path)
      const float2 xv = *(const float2*)(y_train + ((size_t)bb * TT + (NST - 1)) * 2);
      const float si = fmaf(w.wii1, xv.y, fmaf(w.wii0, xv.x, w.bi));
      const float sf = fmaf(w.wif1, xv.y, fmaf(w.wif0, xv.x, w.bf));
      const float sg = fmaf(w.wig1, xv.y, fmaf(w.wig0, xv.x, w.bg));
      const float so = fmaf(w.wio1, xv.y, fmaf(w.wio0, xv.x, w.bo));
      gates_tail(w, si, sf, sg, so, h0, h1, c);
    }

    const float* up = u_train + ((size_t)bb * TT + NST) * 2;
    float*       op = out     + ((size_t)bb * TT + NST) * 2;

    float2 xb[PF];
#pragma unroll
    for (int k = 0; k < PF; ++k) xb[k] = *(const float2*)(up + 2 * k);

    for (int t = 0; t < NST; t += PF) {
#pragma unroll
      for (int k = 0; k < PF; ++k) {
        const float x0 = xb[k].x, x1 = xb[k].y;
        const int tn = t + k + PF;
        if (tn < NST) xb[k] = *(const float2*)(up + (size_t)tn * 2);
        // base (x-dependent) part schedules off the critical chain
        const float bi = fmaf(w.wii1, x1, fmaf(w.wii0, x0, w.bi));
        const float bf = fmaf(w.wif1, x1, fmaf(w.wif0, x0, w.bf));
        const float bg = fmaf(w.wig1, x1, fmaf(w.wig0, x0, w.bg));
        const float bo = fmaf(w.wio1, x1, fmaf(w.wio0, x0, w.bo));
        const float si = fmaf(w.whi1, h1, fmaf(w.whi0, h0, bi));
        const float sf = fmaf(w.whf1, h1, fmaf(w.whf0, h0, bf));
        const float sg = fmaf(w.whg1, h1, fmaf(w.whg0, h0, bg));
        const float so = fmaf(w.who1, h1, fmaf(w.who0, h0, bo));
        gates_tail(w, si, sf, sg, so, h0, h1, c);
        if (hh == 0) *(float2*)(op + (size_t)(t + k) * 2) = make_float2(h0, h1);
      }
    }
  } else {
    // ---------------- Phase 1: parallel teacher-forced ----------------
    const int gid = (blockIdx.x - 4) * 16 + grp;  // 0 .. B*NST-1
    const int bb  = gid >> 12;                    // /4096
    const int t   = gid & (NST - 1);
    GW w;
    load_w<false>(Wih, Whh, bih, bhh, Whr, hh, w);
    const float2 xv = *(const float2*)(y_train + ((size_t)bb * TT + t) * 2);
    const float si = fmaf(w.wii1, xv.y, fmaf(w.wii0, xv.x, w.bi));
    const float sf = fmaf(w.wif1, xv.y, fmaf(w.wif0, xv.x, w.bf));
    const float sg = fmaf(w.wig1, xv.y, fmaf(w.wig0, xv.x, w.bg));
    const float so = fmaf(w.wio1, xv.y, fmaf(w.wio0, xv.x, w.bo));
    float h0, h1, c = 0.f;
    gates_tail(w, si, sf, sg, so, h0, h1, c);
    if (hh == 0) *(float2*)(out + ((size_t)bb * TT + t) * 2) = make_float2(h0, h1);
  }
}

extern "C" void kernel_launch(void* const* d_in, const int* in_sizes, int n_in,
                              void* d_out, int out_size, void* d_ws, size_t ws_size,
                              hipStream_t stream) {
  const float* u_train = (const float*)d_in[0];
  const float* y_train = (const float*)d_in[1];
  const float* Wih     = (const float*)d_in[2];
  const float* Whh     = (const float*)d_in[3];
  const float* bih     = (const float*)d_in[4];
  const float* bhh     = (const float*)d_in[5];
  const float* Whr     = (const float*)d_in[6];
  float* out = (float*)d_out;

  // blocks 0..3: the 64-batch scan (16 lanes/batch, 16 batches/block).
  // blocks 4.. : phase-1 groups, 16 per block -> B*NST/16 = 16384 blocks.
  const int grid = 4 + (BB * NST) / 16;
  openlstm_kernel<<<grid, 256, 0, stream>>>(u_train, y_train, Wih, Whh, bih,
                                            bhh, Whr, out);
}

// Round 5
// 656.391 us; speedup vs baseline: 1.2059x; 1.2059x over previous
//
#include <hip/hip_runtime.h>

// OpenLSTM: B=64, T=8192, nstep=4096, HIDDEN=16, PROJ=2, INPUT=2
// Phase 1 (t<4096): parallel, gates from W_ih@x+b only, c1=i*g.
// Phase 2 (t>=4096): sequential scan, latency-bound.
//   64 lanes per batch, one gate-row per lane (rows 0..3 = i,f,g,o blocks).
//   Cross-row redistribution via ds_bpermute (unambiguous full-wave gather)
//   instead of permlane*_swap (r3/r4 failure: unverifiable semantics).

#define BB   64
#define TT   8192
#define NST  4096
#define PF   16

static __device__ __forceinline__ float fast_exp2(float x) {
#if __has_builtin(__builtin_amdgcn_exp2f)
  return __builtin_amdgcn_exp2f(x);
#else
  return exp2f(x);
#endif
}
static __device__ __forceinline__ float fast_rcp(float x) {
#if __has_builtin(__builtin_amdgcn_rcpf)
  return __builtin_amdgcn_rcpf(x);
#else
  return 1.0f / x;
#endif
}

// add value rotated by N within each 16-lane row (row_ror:N = 0x120|N)
// PROVEN by round-2 PASS.
template <int CTRL>
static __device__ __forceinline__ float rr_add(float x) {
  int r = __builtin_amdgcn_update_dpp(0, __builtin_bit_cast(int, x), CTRL, 0xF, 0xF, true);
  return x + __builtin_bit_cast(float, r);
}

// full-wave lane gather: value of lane (addr4>>2)
static __device__ __forceinline__ float bperm(int addr4, float v) {
  return __builtin_bit_cast(float,
      __builtin_amdgcn_ds_bpermute(addr4, __builtin_bit_cast(int, v)));
}

// ---------------- scan (phase 2) per-lane state ----------------
struct SW {
  float w0, w1, wh0, wh1, b;  // this lane's gate row, pre-scaled
  float m, n;                 // activation affine: sigmoid=(1,0), tanh=(2,-1)
  float whr, whr2;            // whr_sel, -2*whr_sel (row parity -> Whr row 0/1)
  int ai, af, ag, ao;         // bpermute byte-addrs: lanes hh,16+hh,32+hh,48+hh
};

static __device__ __forceinline__ void scan_step(const SW& w, float x0, float x1,
                                                 float& h0, float& h1, float& c) {
  const float bse = fmaf(w.w1, x1, fmaf(w.w0, x0, w.b));      // off-chain
  const float s   = fmaf(w.wh1, h1, fmaf(w.wh0, h0, bse));
  const float d   = fast_rcp(1.f + fast_exp2(s));
  const float a   = fmaf(d, w.m, w.n);                         // sigmoid or tanh
  const float gi = bperm(w.ai, a);   // i-activation of unit hh (from row 0)
  const float gf = bperm(w.af, a);   // f (row 1)
  const float gg = bperm(w.ag, a);   // g (row 2)
  const float go = bperm(w.ao, a);   // o (row 3)
  c = fmaf(gf, c, gi * gg);
  const float owhr  = go * w.whr;                              // off-chain vs rcp
  const float owhr2 = go * w.whr2;
  const float r2 = fast_rcp(1.f + fast_exp2(c * 2.8853900817779268f));
  float p = fmaf(r2, owhr2, owhr);   // = o*tanh(c)*whr_sel
  p = rr_add<0x128>(p);
  p = rr_add<0x124>(p);
  p = rr_add<0x122>(p);
  p = rr_add<0x121>(p);              // full row-sum in every lane of each row
  h0 = bperm(w.ai, p);               // row 0 (even parity) holds h0
  h1 = bperm(w.af, p);               // row 1 (odd parity)  holds h1
}

__global__ __launch_bounds__(256) void openlstm_kernel(
    const float* __restrict__ u_train, const float* __restrict__ y_train,
    const float* __restrict__ Wih, const float* __restrict__ Whh,
    const float* __restrict__ bih, const float* __restrict__ bhh,
    const float* __restrict__ Whr, float* __restrict__ out) {
  const int tid = threadIdx.x;
  const float S1 = -1.4426950408889634f;   // -log2(e)
  const float S2 = -2.8853900817779268f;   // -2*log2(e)

  if (blockIdx.x < 16) {
    // ---------------- Phase 2: sequential scan ----------------
    const int lane = tid & 63;
    const int wv   = tid >> 6;                   // wave in block
    const int bb   = blockIdx.x * 4 + wv;        // batch 0..63
    const int hh   = lane & 15;
    const int r    = lane >> 4;                  // row 0..3 = gate block i,f,g,o
    const int wrow = r * 16 + hh;                // reference gate row
    const bool isg = (r == 2);
    const float sc = isg ? S2 : S1;

    SW w;
    w.w0  = Wih[2 * wrow] * sc;  w.w1  = Wih[2 * wrow + 1] * sc;
    w.wh0 = Whh[2 * wrow] * sc;  w.wh1 = Whh[2 * wrow + 1] * sc;
    w.b   = (bih[wrow] + bhh[wrow]) * sc;
    w.m   = isg ? 2.f : 1.f;
    w.n   = isg ? -1.f : 0.f;
    const float whr_sel = (r & 1) ? Whr[16 + hh] : Whr[hh];
    w.whr  = whr_sel;
    w.whr2 = -2.f * whr_sel;
    w.ai = 4 * hh;
    w.af = 4 * (16 + hh);
    w.ag = 4 * (32 + hh);
    w.ao = 4 * (48 + hh);

    float h0 = 0.f, h1 = 0.f, c = 0.f;
    {
      // initial carry from y_train[bb, NST-1, :]  (h=0, c=0 path)
      const float2 xv = *(const float2*)(y_train + ((size_t)bb * TT + (NST - 1)) * 2);
      scan_step(w, xv.x, xv.y, h0, h1, c);
    }

    const float* up = u_train + ((size_t)bb * TT + NST) * 2;
    float*       ob = out     + ((size_t)bb * TT + NST) * 2;

    float2 xb[PF];
#pragma unroll
    for (int k = 0; k < PF; ++k) xb[k] = *(const float2*)(up + 2 * k);

    const int  cslot = lane >> 1;    // lanes 0-31 capture steps 0..15 of window
    const bool odd   = lane & 1;
    float cap = 0.f;

    for (int t = 0; t < NST; t += PF) {
#pragma unroll
      for (int k = 0; k < PF; ++k) {
        const float x0 = xb[k].x, x1 = xb[k].y;
        int tn = t + k + PF;
        tn = (tn < NST) ? tn : (NST - 1);        // branchless clamp (uniform)
        xb[k] = *(const float2*)(up + (size_t)tn * 2);
        scan_step(w, x0, x1, h0, h1, c);
        const float hsel = odd ? h1 : h0;
        cap = (cslot == k) ? hsel : cap;         // branchless capture
      }
      if (lane < 32) ob[(size_t)t * 2 + lane] = cap;  // 128B coalesced / window
    }
  } else {
    // ---------------- Phase 1: parallel teacher-forced (r2-proven) --------
    const int hh  = tid & 15;
    const int grp = tid >> 4;
    const int gid = (blockIdx.x - 16) * 16 + grp;  // 0 .. B*NST-1
    const int bb  = gid >> 12;                     // /4096
    const int t   = gid & (NST - 1);
    const int ri = hh, rg = hh + 32, ro = hh + 48;

    const float wii0 = Wih[2 * ri] * S1, wii1 = Wih[2 * ri + 1] * S1;
    const float wig0 = Wih[2 * rg] * S2, wig1 = Wih[2 * rg + 1] * S2;
    const float wio0 = Wih[2 * ro] * S1, wio1 = Wih[2 * ro + 1] * S1;
    const float bi = (bih[ri] + bhh[ri]) * S1;
    const float bg = (bih[rg] + bhh[rg]) * S2;
    const float bo = (bih[ro] + bhh[ro]) * S1;
    const float whr0 = Whr[hh], whr1 = Whr[16 + hh];

    const float2 xv = *(const float2*)(y_train + ((size_t)bb * TT + t) * 2);
    const float si = fmaf(wii1, xv.y, fmaf(wii0, xv.x, bi));
    const float sg = fmaf(wig1, xv.y, fmaf(wig0, xv.x, bg));
    const float so = fmaf(wio1, xv.y, fmaf(wio0, xv.x, bo));
    const float gi = fast_rcp(1.f + fast_exp2(si));
    const float gg = fmaf(2.f, fast_rcp(1.f + fast_exp2(sg)), -1.f);
    const float go = fast_rcp(1.f + fast_exp2(so));
    const float c1 = gi * gg;   // c0 = 0
    const float tc = fmaf(-2.f, fast_rcp(1.f + fast_exp2(c1 * 2.8853900817779268f)), 1.f);
    const float v  = go * tc;
    float p0 = v * whr0;
    float p1 = v * whr1;
    p0 = rr_add<0x128>(p0); p1 = rr_add<0x128>(p1);
    p0 = rr_add<0x124>(p0); p1 = rr_add<0x124>(p1);
    p0 = rr_add<0x122>(p0); p1 = rr_add<0x122>(p1);
    p0 = rr_add<0x121>(p0); p1 = rr_add<0x121>(p1);
    if (hh == 0) *(float2*)(out + ((size_t)bb * TT + t) * 2) = make_float2(p0, p1);
  }
}

extern "C" void kernel_launch(void* const* d_in, const int* in_sizes, int n_in,
                              void* d_out, int out_size, void* d_ws, size_t ws_size,
                              hipStream_t stream) {
  const float* u_train = (const float*)d_in[0];
  const float* y_train = (const float*)d_in[1];
  const float* Wih     = (const float*)d_in[2];
  const float* Whh     = (const float*)d_in[3];
  const float* bih     = (const float*)d_in[4];
  const float* bhh     = (const float*)d_in[5];
  const float* Whr     = (const float*)d_in[6];
  float* out = (float*)d_out;

  // blocks 0..15: scan (4 batches/block, 64 lanes per batch).
  // blocks 16.. : phase-1 groups, 16 per block -> B*NST/16 = 16384 blocks.
  const int grid = 16 + (BB * NST) / 16;
  openlstm_kernel<<<grid, 256, 0, stream>>>(u_train, y_train, Wih, Whh, bih,
                                            bhh, Whr, out);
}

// Round 6
// 457.759 us; speedup vs baseline: 1.7292x; 1.4339x over previous
//
#include <hip/hip_runtime.h>

// OpenLSTM: B=64, T=8192, nstep=4096, HIDDEN=16, PROJ=2, INPUT=2
// Phase 1 (t<4096): parallel, gates from W_ih@x+b only, c1=i*g.
// Phase 2 (t>=4096): sequential scan, latency-bound.
//   r6 layout: UNIT-MAJOR quads — lane = 4*hh + r (hh=unit, r=gate i/f/g/o).
//   Gate redistribution via quad_perm DPP (VALU pipe), projection reduce via
//   row_ror + row_bcast15/31 DPP adds + v_readlane -> SGPR h0,h1.
//   ZERO DS-pipe ops in the scan loop (r5 post-mortem: 2 bpermute waits
//   ~100cy each dominated the 350cy/step chain).

#define BB   64
#define TT   8192
#define NST  4096
#define PF   16

static __device__ __forceinline__ float fast_exp2(float x) {
#if __has_builtin(__builtin_amdgcn_exp2f)
  return __builtin_amdgcn_exp2f(x);
#else
  return exp2f(x);
#endif
}
static __device__ __forceinline__ float fast_rcp(float x) {
#if __has_builtin(__builtin_amdgcn_rcpf)
  return __builtin_amdgcn_rcpf(x);
#else
  return 1.0f / x;
#endif
}

// x + dpp_perm(x): CTRL = row_ror:N (0x120|N), row_bcast15 (0x142),
// row_bcast31 (0x143). bound_ctrl=1 -> invalid src reads 0 (additive id).
// row_ror proven by r2/r5 PASS.
template <int CTRL>
static __device__ __forceinline__ float rr_add(float x) {
  int r = __builtin_amdgcn_update_dpp(0, __builtin_bit_cast(int, x), CTRL, 0xF, 0xF, true);
  return x + __builtin_bit_cast(float, r);
}

// quad_perm broadcast of quad-lane Q to all 4 lanes of the quad.
template <int SEL>  // 0x00,0x55,0xAA,0xFF
static __device__ __forceinline__ float qperm(float x) {
  int r = __builtin_amdgcn_update_dpp(0, __builtin_bit_cast(int, x), SEL, 0xF, 0xF, true);
  return __builtin_bit_cast(float, r);
}

static __device__ __forceinline__ float rdlane63(float x) {
  return __builtin_bit_cast(float,
      __builtin_amdgcn_readlane(__builtin_bit_cast(int, x), 63));
}

// ---------------- scan (phase 2) per-lane state ----------------
struct SW {
  float w0, w1, wh0, wh1, b;      // this lane's gate row, pre-scaled
  float m, n;                      // activation affine: sigmoid=(1,0), tanh=(2,-1)
  float whr0, whr0m2, whr1, whr1m2;// Whr[0,hh], -2*that, Whr[1,hh], -2*that
};

static __device__ __forceinline__ void scan_step(const SW& w, float x0, float x1,
                                                 float& h0, float& h1, float& c) {
  const float bse = fmaf(w.w1, x1, fmaf(w.w0, x0, w.b));      // off-chain
  float s = fmaf(w.wh0, h0, bse);                              // h0,h1 are SGPR-uniform
  s = fmaf(w.wh1, h1, s);
  const float d = fast_rcp(1.f + fast_exp2(s));
  const float a = fmaf(d, w.m, w.n);                           // sigmoid or tanh
  const float gi = qperm<0x00>(a);                             // quad lane 0 = i
  const float gf = qperm<0x55>(a);                             // lane 1 = f
  const float gg = qperm<0xAA>(a);                             // lane 2 = g
  const float go = qperm<0xFF>(a);                             // lane 3 = o
  c = fmaf(gf, c, gi * gg);                                    // quad-redundant
  const float o0  = go * w.whr0;                               // off-chain vs tanh(c)
  const float o0m = go * w.whr0m2;
  const float o1  = go * w.whr1;
  const float o1m = go * w.whr1m2;
  const float r2 = fast_rcp(1.f + fast_exp2(c * 2.8853900817779268f));
  float p0 = fmaf(r2, o0m, o0);    // = o*tanh(c)*Whr[0,hh]
  float p1 = fmaf(r2, o1m, o1);    // = o*tanh(c)*Whr[1,hh]
  // wave-wide sum, each unit exactly once (quads are uniform):
  p0 = rr_add<0x124>(p0); p1 = rr_add<0x124>(p1);   // + ror4  (2 quads)
  p0 = rr_add<0x128>(p0); p1 = rr_add<0x128>(p1);   // + ror8  (row: 4 units)
  p0 = rr_add<0x142>(p0); p1 = rr_add<0x142>(p1);   // bcast15: row pairs
  p0 = rr_add<0x143>(p0); p1 = rr_add<0x143>(p1);   // bcast31: lane63 = total
  h0 = rdlane63(p0);
  h1 = rdlane63(p1);
}

__global__ __launch_bounds__(256) void openlstm_kernel(
    const float* __restrict__ u_train, const float* __restrict__ y_train,
    const float* __restrict__ Wih, const float* __restrict__ Whh,
    const float* __restrict__ bih, const float* __restrict__ bhh,
    const float* __restrict__ Whr, float* __restrict__ out) {
  const int tid = threadIdx.x;
  const float S1 = -1.4426950408889634f;   // -log2(e)
  const float S2 = -2.8853900817779268f;   // -2*log2(e)

  if (blockIdx.x < 16) {
    // ---------------- Phase 2: sequential scan ----------------
    const int lane = tid & 63;
    const int wv   = tid >> 6;                   // wave in block
    const int bb   = blockIdx.x * 4 + wv;        // batch 0..63
    const int hh   = lane >> 2;                  // unit 0..15
    const int r    = lane & 3;                   // gate 0..3 = i,f,g,o
    const int wrow = r * 16 + hh;                // reference gate row
    const bool isg = (r == 2);
    const float sc = isg ? S2 : S1;

    SW w;
    w.w0  = Wih[2 * wrow] * sc;  w.w1  = Wih[2 * wrow + 1] * sc;
    w.wh0 = Whh[2 * wrow] * sc;  w.wh1 = Whh[2 * wrow + 1] * sc;
    w.b   = (bih[wrow] + bhh[wrow]) * sc;
    w.m   = isg ? 2.f : 1.f;
    w.n   = isg ? -1.f : 0.f;
    w.whr0   = Whr[hh];
    w.whr0m2 = -2.f * w.whr0;
    w.whr1   = Whr[16 + hh];
    w.whr1m2 = -2.f * w.whr1;

    float h0 = 0.f, h1 = 0.f, c = 0.f;
    {
      // initial carry from y_train[bb, NST-1, :]  (h=0, c=0 path)
      const float2 xv = *(const float2*)(y_train + ((size_t)bb * TT + (NST - 1)) * 2);
      scan_step(w, xv.x, xv.y, h0, h1, c);
    }

    const float* up = u_train + ((size_t)bb * TT + NST) * 2;
    float*       ob = out     + ((size_t)bb * TT + NST) * 2;

    float2 xb[PF];
#pragma unroll
    for (int k = 0; k < PF; ++k) xb[k] = *(const float2*)(up + 2 * k);

    const int  cslot = lane >> 1;    // lanes 0-31 capture steps 0..15 of window
    const bool odd   = lane & 1;
    float cap = 0.f;

    for (int t = 0; t < NST; t += PF) {
#pragma unroll
      for (int k = 0; k < PF; ++k) {
        const float x0 = xb[k].x, x1 = xb[k].y;
        int tn = t + k + PF;
        tn = (tn < NST) ? tn : (NST - 1);        // branchless clamp (uniform)
        xb[k] = *(const float2*)(up + (size_t)tn * 2);
        scan_step(w, x0, x1, h0, h1, c);
        const float hsel = odd ? h1 : h0;        // h0,h1 wave-uniform
        cap = (cslot == k) ? hsel : cap;         // branchless capture
      }
      if (lane < 32) ob[(size_t)t * 2 + lane] = cap;  // 128B coalesced / window
    }
  } else {
    // ---------------- Phase 1: parallel teacher-forced (r2/r5-proven) -----
    const int hh  = tid & 15;
    const int grp = tid >> 4;
    const int gid = (blockIdx.x - 16) * 16 + grp;  // 0 .. B*NST-1
    const int bb  = gid >> 12;                     // /4096
    const int t   = gid & (NST - 1);
    const int ri = hh, rg = hh + 32, ro = hh + 48;

    const float wii0 = Wih[2 * ri] * S1, wii1 = Wih[2 * ri + 1] * S1;
    const float wig0 = Wih[2 * rg] * S2, wig1 = Wih[2 * rg + 1] * S2;
    const float wio0 = Wih[2 * ro] * S1, wio1 = Wih[2 * ro + 1] * S1;
    const float bi = (bih[ri] + bhh[ri]) * S1;
    const float bg = (bih[rg] + bhh[rg]) * S2;
    const float bo = (bih[ro] + bhh[ro]) * S1;
    const float whr0 = Whr[hh], whr1 = Whr[16 + hh];

    const float2 xv = *(const float2*)(y_train + ((size_t)bb * TT + t) * 2);
    const float si = fmaf(wii1, xv.y, fmaf(wii0, xv.x, bi));
    const float sg = fmaf(wig1, xv.y, fmaf(wig0, xv.x, bg));
    const float so = fmaf(wio1, xv.y, fmaf(wio0, xv.x, bo));
    const float gi = fast_rcp(1.f + fast_exp2(si));
    const float gg = fmaf(2.f, fast_rcp(1.f + fast_exp2(sg)), -1.f);
    const float go = fast_rcp(1.f + fast_exp2(so));
    const float c1 = gi * gg;   // c0 = 0
    const float tc = fmaf(-2.f, fast_rcp(1.f + fast_exp2(c1 * 2.8853900817779268f)), 1.f);
    const float v  = go * tc;
    float p0 = v * whr0;
    float p1 = v * whr1;
    p0 = rr_add<0x128>(p0); p1 = rr_add<0x128>(p1);
    p0 = rr_add<0x124>(p0); p1 = rr_add<0x124>(p1);
    p0 = rr_add<0x122>(p0); p1 = rr_add<0x122>(p1);
    p0 = rr_add<0x121>(p0); p1 = rr_add<0x121>(p1);
    if (hh == 0) *(float2*)(out + ((size_t)bb * TT + t) * 2) = make_float2(p0, p1);
  }
}

extern "C" void kernel_launch(void* const* d_in, const int* in_sizes, int n_in,
                              void* d_out, int out_size, void* d_ws, size_t ws_size,
                              hipStream_t stream) {
  const float* u_train = (const float*)d_in[0];
  const float* y_train = (const float*)d_in[1];
  const float* Wih     = (const float*)d_in[2];
  const float* Whh     = (const float*)d_in[3];
  const float* bih     = (const float*)d_in[4];
  const float* bhh     = (const float*)d_in[5];
  const float* Whr     = (const float*)d_in[6];
  float* out = (float*)d_out;

  // blocks 0..15: scan (4 batches/block, 64 lanes per batch).
  // blocks 16.. : phase-1 groups, 16 per block -> B*NST/16 = 16384 blocks.
  const int grid = 16 + (BB * NST) / 16;
  openlstm_kernel<<<grid, 256, 0, stream>>>(u_train, y_train, Wih, Whh, bih,
                                            bhh, Whr, out);
}